// Round 1
// baseline (3366.008 us; speedup 1.0000x reference)
//
#include <hip/hip_runtime.h>

namespace {

constexpr int kB = 16;
constexpr int kM = 1024;
constexpr int kT = 4096;
constexpr int kD = 512;

// ---------------- gather rows of emb into dst ----------------
__global__ __launch_bounds__(256) void gather_rows_k(
    const float4* __restrict__ embv, const int* __restrict__ ids,
    float4* __restrict__ outv, int nrows)
{
  int idx = blockIdx.x * 256 + threadIdx.x;
  int total = nrows * 128;  // 128 float4 per 512-float row
  if (idx >= total) return;
  int row = idx >> 7;
  int d4  = idx & 127;
  int id  = ids[row];
  outv[idx] = embv[(size_t)id * 128 + d4];
}

// ---------------- CSR build: one block per batch ----------------
// deg[b,m]  = #masked triples with tail==m plus #masked with head==m  (== cnt)
// entries (deterministic t-ascending order): (src node, triple idx)
__global__ __launch_bounds__(1024) void build_csr_k(
    const int* __restrict__ headp, const int* __restrict__ tailp,
    const int* __restrict__ lblp,
    int* __restrict__ deg, int* __restrict__ rowstart,
    int* __restrict__ esrc, int* __restrict__ erel)
{
  __shared__ int sh[kT];
  __shared__ int st[kT];
  __shared__ int sl[kT];
  __shared__ int sscan[kM];
  int b = blockIdx.x;
  int tid = threadIdx.x;
  for (int i = tid; i < kT; i += 1024) {
    sh[i] = headp[b * kT + i];
    st[i] = tailp[b * kT + i];
    sl[i] = lblp[b * kT + i];
  }
  __syncthreads();
  const int m = tid;  // blockDim == kM
  int dg = 0;
  for (int t = 0; t < kT; ++t) {
    int msk = (sl[t] != -1) ? 1 : 0;
    dg += msk & (int)(st[t] == m);
    dg += msk & (int)(sh[t] == m);
  }
  sscan[tid] = dg;
  __syncthreads();
  // Hillis-Steele inclusive scan over 1024
  for (int off = 1; off < kM; off <<= 1) {
    int add = (tid >= off) ? sscan[tid - off] : 0;
    __syncthreads();
    sscan[tid] += add;
    __syncthreads();
  }
  int excl = sscan[tid] - dg;
  int rs = b * (2 * kT) + excl;
  deg[b * kM + m] = dg;
  rowstart[b * kM + m] = rs;
  int ptr = rs;
  for (int t = 0; t < kT; ++t) {
    if (sl[t] == -1) continue;
    if (st[t] == m) { esrc[ptr] = sh[t]; erel[ptr] = t; ++ptr; }
    if (sh[t] == m) { esrc[ptr] = st[t]; erel[ptr] = t; ++ptr; }
  }
}

// ---------------- U = (scatter-aggregated messages) / max(cnt,1) ----------------
__global__ __launch_bounds__(128) void compute_upd_k(
    const float4* __restrict__ Xv, const float4* __restrict__ Rv,
    const int* __restrict__ deg, const int* __restrict__ rowstart,
    const int* __restrict__ esrc, const int* __restrict__ erel,
    float4* __restrict__ Uv)
{
  int bm = blockIdx.x;
  int b = bm >> 10;
  int tid = threadIdx.x;  // 128 threads x float4 = 512 floats
  int dg = deg[bm];
  int rs = rowstart[bm];
  float ax = 0.f, ay = 0.f, az = 0.f, aw = 0.f;
  size_t xbase = (size_t)b * kM * 128;
  size_t rbase = (size_t)b * kT * 128;
  for (int e = 0; e < dg; ++e) {
    int src = esrc[rs + e];
    int rl  = erel[rs + e];
    float4 xv = Xv[xbase + (size_t)src * 128 + tid];
    float4 rv = Rv[rbase + (size_t)rl * 128 + tid];
    ax += xv.x - rv.x;
    ay += xv.y - rv.y;
    az += xv.z - rv.z;
    aw += xv.w - rv.w;
  }
  float s = 1.0f / (float)(dg > 0 ? dg : 1);
  float4 o;
  o.x = ax * s; o.y = ay * s; o.z = az * s; o.w = aw * s;
  Uv[(size_t)bm * 128 + tid] = o;
}

// ---------------- full-row GEMM: C[r, 0:512] = f( A(r,:) . W^T ) ----------------
// MODE 0: C = relu(X.Ws^T + U.Wn^T), in-place into X.  K=1024
// MODE 1: C = REL.Wr^T, in-place into REL.             K=512
// MODE 2: C = Xh.Wt1^T + REL.Wt2^T + Xt.Wt3^T -> out.  K=1536 (in-place over REL)
// 64 rows/block, 512 threads, 8x8 micro-tile, K-chunk 16.
template<int MODE>
__global__ __launch_bounds__(512) void gemm_rows_k(
    const float* __restrict__ X,
    const float* __restrict__ U,
    const float* __restrict__ REL,
    const float* __restrict__ W1,
    const float* __restrict__ W2,
    const int* __restrict__ headp,
    const int* __restrict__ tailp,
    float* __restrict__ C)
{
  constexpr int KTOT = (MODE == 0) ? 1024 : (MODE == 1) ? 512 : 1536;
  constexpr int NCHUNK = KTOT / 16;
  __shared__ float As[16][68];    // [k][row], padded: 16B-aligned float4 reads
  __shared__ float Wls[16][516];  // [k][col]
  const int tid = threadIdx.x;
  const int ty = tid >> 6;   // 0..7  (8 rows each)
  const int tx = tid & 63;   // 0..63 (8 cols each)
  const int rowBase = blockIdx.x * 64;

  float acc[8][8];
#pragma unroll
  for (int i = 0; i < 8; ++i)
#pragma unroll
    for (int j = 0; j < 8; ++j) acc[i][j] = 0.f;

  // A-loader setup (threads 0..255): 64 rows x 4 float4-chunks of k
  const float* pa0 = nullptr;
  const float* pa1 = nullptr;
  const float* pa2 = nullptr;
  const int ak4 = tid & 3;
  if (tid < 256) {
    int lr = tid >> 2;
    int r = rowBase + lr;
    if constexpr (MODE == 0) {
      pa0 = X + (size_t)r * kD;
      pa1 = U + (size_t)r * kD;
    } else if constexpr (MODE == 1) {
      pa0 = REL + (size_t)r * kD;
    } else {
      int b = r >> 12;  // T = 4096
      int hid = headp[r];
      int tl  = tailp[r];
      pa0 = X + (size_t)(b * kM + hid) * kD;
      pa1 = REL + (size_t)r * kD;
      pa2 = X + (size_t)(b * kM + tl) * kD;
    }
  }

  for (int kc = 0; kc < NCHUNK; ++kc) {
    __syncthreads();
    // ---- stage A tile (transposed) ----
    if (tid < 256) {
      int lr = tid >> 2;
      int kg = kc * 16 + ak4 * 4;
      const float* ap;
      if constexpr (MODE == 0) {
        ap = (kg < 512) ? (pa0 + kg) : (pa1 + (kg - 512));
      } else if constexpr (MODE == 1) {
        ap = pa0 + kg;
      } else {
        ap = (kg < 512) ? (pa0 + kg)
           : (kg < 1024) ? (pa1 + (kg - 512))
                         : (pa2 + (kg - 1024));
      }
      float4 a = *(const float4*)ap;
      int k0 = ak4 * 4;
      As[k0 + 0][lr] = a.x;
      As[k0 + 1][lr] = a.y;
      As[k0 + 2][lr] = a.z;
      As[k0 + 3][lr] = a.w;
    }
    // ---- stage W tile (transposed): 512 cols x 16 k ----
#pragma unroll
    for (int i = 0; i < 4; ++i) {
      int idx = tid + i * 512;
      int e = idx >> 2;
      int k4 = idx & 3;
      int kg = kc * 16 + k4 * 4;
      const float* wp;
      if constexpr (MODE == 0) {
        wp = (kg < 512) ? (W1 + (size_t)e * 512 + kg)
                        : (W2 + (size_t)e * 512 + (kg - 512));
      } else if constexpr (MODE == 1) {
        wp = W1 + (size_t)e * 512 + kg;
      } else {
        wp = W1 + (size_t)e * 1536 + kg;
      }
      float4 w = *(const float4*)wp;
      int k0 = k4 * 4;
      Wls[k0 + 0][e] = w.x;
      Wls[k0 + 1][e] = w.y;
      Wls[k0 + 2][e] = w.z;
      Wls[k0 + 3][e] = w.w;
    }
    __syncthreads();
    // ---- compute ----
#pragma unroll
    for (int kk = 0; kk < 16; ++kk) {
      float4 a0 = *(const float4*)&As[kk][ty * 8];
      float4 a1 = *(const float4*)&As[kk][ty * 8 + 4];
      float4 w0 = *(const float4*)&Wls[kk][tx * 8];
      float4 w1 = *(const float4*)&Wls[kk][tx * 8 + 4];
      float a_[8] = {a0.x, a0.y, a0.z, a0.w, a1.x, a1.y, a1.z, a1.w};
      float w_[8] = {w0.x, w0.y, w0.z, w0.w, w1.x, w1.y, w1.z, w1.w};
#pragma unroll
      for (int i = 0; i < 8; ++i)
#pragma unroll
        for (int j = 0; j < 8; ++j)
          acc[i][j] = fmaf(a_[i], w_[j], acc[i][j]);
    }
  }

  // ---- epilogue: write own rows (in-place safe: block reads only its rows) ----
#pragma unroll
  for (int i = 0; i < 8; ++i) {
    int r = rowBase + ty * 8 + i;
    float* cp = C + (size_t)r * kD + tx * 8;
    float4 v0, v1;
    v0.x = acc[i][0]; v0.y = acc[i][1]; v0.z = acc[i][2]; v0.w = acc[i][3];
    v1.x = acc[i][4]; v1.y = acc[i][5]; v1.z = acc[i][6]; v1.w = acc[i][7];
    if constexpr (MODE == 0) {
      v0.x = fmaxf(v0.x, 0.f); v0.y = fmaxf(v0.y, 0.f);
      v0.z = fmaxf(v0.z, 0.f); v0.w = fmaxf(v0.w, 0.f);
      v1.x = fmaxf(v1.x, 0.f); v1.y = fmaxf(v1.y, 0.f);
      v1.z = fmaxf(v1.z, 0.f); v1.w = fmaxf(v1.w, 0.f);
    }
    *(float4*)cp = v0;
    *(float4*)(cp + 4) = v1;
  }
}

// ---------------- encoded_cause reduction (2-pass, deterministic) ----------------
__global__ __launch_bounds__(128) void reduce1_k(
    const float4* __restrict__ outv, float4* __restrict__ part)
{
  int blk = blockIdx.x;
  int b = blk >> 4;
  int c = blk & 15;
  int tid = threadIdx.x;
  float ax = 0.f, ay = 0.f, az = 0.f, aw = 0.f;
  size_t base = ((size_t)b * kT + (size_t)c * 256) * 128;
  for (int t = 0; t < 256; ++t) {
    float4 v = outv[base + (size_t)t * 128 + tid];
    ax += v.x; ay += v.y; az += v.z; aw += v.w;
  }
  float4 o; o.x = ax; o.y = ay; o.z = az; o.w = aw;
  part[(size_t)blk * 128 + tid] = o;
}

__global__ __launch_bounds__(128) void reduce2_k(
    const float4* __restrict__ part, float4* __restrict__ enc)
{
  int b = blockIdx.x;
  int tid = threadIdx.x;
  float ax = 0.f, ay = 0.f, az = 0.f, aw = 0.f;
  for (int c = 0; c < 16; ++c) {
    float4 v = part[((size_t)(b * 16 + c)) * 128 + tid];
    ax += v.x; ay += v.y; az += v.z; aw += v.w;
  }
  float4 o; o.x = ax; o.y = ay; o.z = az; o.w = aw;
  enc[(size_t)b * 128 + tid] = o;
}

}  // namespace

extern "C" void kernel_launch(void* const* d_in, const int* in_sizes, int n_in,
                              void* d_out, int out_size, void* d_ws, size_t ws_size,
                              hipStream_t stream) {
  const float* emb = (const float*)d_in[0];
  const float* Ws  = (const float*)d_in[1];
  const float* Wn  = (const float*)d_in[2];
  const float* Wr  = (const float*)d_in[3];
  const float* Wt  = (const float*)d_in[4];
  const int* cid   = (const int*)d_in[5];
  const int* relid = (const int*)d_in[6];
  const int* headp = (const int*)d_in[7];
  const int* tailp = (const int*)d_in[8];
  const int* lblp  = (const int*)d_in[9];
  float* out = (float*)d_out;

  // workspace layout (bytes): X(32M) U(32M) deg(64K) rowstart(64K) esrc(512K) erel(512K) part(512K)
  float* X = (float*)d_ws;
  float* U = X + (size_t)kB * kM * kD;
  int* deg = (int*)(U + (size_t)kB * kM * kD);
  int* rowstart = deg + kB * kM;
  int* esrc = rowstart + kB * kM;
  int* erel = esrc + kB * 2 * kT;
  float* part = (float*)(erel + kB * 2 * kT);

  float* REL = out;                               // rel lives in d_out triple region
  float* ENC = out + (size_t)kB * kT * kD;

  // gather node + relation embeddings
  gather_rows_k<<<(kB * kM * 128) / 256, 256, 0, stream>>>(
      (const float4*)emb, cid, (float4*)X, kB * kM);
  gather_rows_k<<<(kB * kT * 128) / 256, 256, 0, stream>>>(
      (const float4*)emb, relid, (float4*)REL, kB * kT);

  // adjacency CSR (hop-invariant)
  build_csr_k<<<kB, 1024, 0, stream>>>(headp, tailp, lblp, deg, rowstart, esrc, erel);

  for (int h = 0; h < 2; ++h) {
    compute_upd_k<<<kB * kM, 128, 0, stream>>>(
        (const float4*)X, (const float4*)REL, deg, rowstart, esrc, erel, (float4*)U);
    gemm_rows_k<0><<<(kB * kM) / 64, 512, 0, stream>>>(
        X, U, REL, Ws + (size_t)h * kD * kD, Wn + (size_t)h * kD * kD, headp, tailp, X);
    gemm_rows_k<1><<<(kB * kT) / 64, 512, 0, stream>>>(
        X, U, REL, Wr + (size_t)h * kD * kD, nullptr, headp, tailp, REL);
  }

  // final triple GEMM (gathers x[head], rel, x[tail]; writes over REL rows in-place)
  gemm_rows_k<2><<<(kB * kT) / 64, 512, 0, stream>>>(
      X, U, REL, Wt, nullptr, headp, tailp, out);

  // encoded_cause = sum over T
  reduce1_k<<<kB * 16, 128, 0, stream>>>((const float4*)out, (float4*)part);
  reduce2_k<<<kB, 128, 0, stream>>>((const float4*)part, (float4*)ENC);
}

// Round 2
// 1070.586 us; speedup vs baseline: 3.1441x; 3.1441x over previous
//
#include <hip/hip_runtime.h>

namespace {

constexpr int kB = 16;
constexpr int kM = 1024;
constexpr int kT = 4096;
constexpr int kD = 512;

typedef __attribute__((ext_vector_type(8))) short bfrag8;
typedef __attribute__((ext_vector_type(4))) float f4acc;

__device__ __forceinline__ ushort f2bf(float f) {
  unsigned u = __float_as_uint(f);
  u += 0x7fffu + ((u >> 16) & 1u);
  return (ushort)(u >> 16);
}
__device__ __forceinline__ float bf2f(ushort h) {
  return __uint_as_float(((unsigned)h) << 16);
}

__device__ __forceinline__ void gload_lds16(const void* g, void* l) {
  __builtin_amdgcn_global_load_lds(
      (const __attribute__((address_space(1))) void*)g,
      (__attribute__((address_space(3))) void*)l, 16, 0, 0);
}

// ---------------- fp32 -> bf16 conversion (weights) ----------------
__global__ __launch_bounds__(256) void cvt_bf16_k(
    const float4* __restrict__ in, ushort4* __restrict__ out, int n4)
{
  int i = blockIdx.x * 256 + threadIdx.x;
  if (i >= n4) return;
  float4 v = in[i];
  ushort4 o;
  o.x = f2bf(v.x); o.y = f2bf(v.y); o.z = f2bf(v.z); o.w = f2bf(v.w);
  out[i] = o;
}

// ---------------- gather emb rows -> bf16 ----------------
__global__ __launch_bounds__(256) void gather_bf16_k(
    const float4* __restrict__ embv, const int* __restrict__ ids,
    ushort4* __restrict__ outv, int nrows)
{
  int i = blockIdx.x * 256 + threadIdx.x;
  if (i >= nrows * 128) return;
  int row = i >> 7;
  int c = i & 127;
  int id = ids[row];
  float4 v = embv[(size_t)id * 128 + c];
  ushort4 o;
  o.x = f2bf(v.x); o.y = f2bf(v.y); o.z = f2bf(v.z); o.w = f2bf(v.w);
  outv[i] = o;
}

// ---------------- CSR build: one block per batch ----------------
__global__ __launch_bounds__(1024) void build_csr_k(
    const int* __restrict__ headp, const int* __restrict__ tailp,
    const int* __restrict__ lblp,
    int* __restrict__ deg, int* __restrict__ rowstart,
    int* __restrict__ esrc, int* __restrict__ erel)
{
  __shared__ int sh[kT];
  __shared__ int st[kT];
  __shared__ int sl[kT];
  __shared__ int sscan[kM];
  int b = blockIdx.x;
  int tid = threadIdx.x;
  for (int i = tid; i < kT; i += 1024) {
    sh[i] = headp[b * kT + i];
    st[i] = tailp[b * kT + i];
    sl[i] = lblp[b * kT + i];
  }
  __syncthreads();
  const int m = tid;
  int dg = 0;
  for (int t = 0; t < kT; ++t) {
    int msk = (sl[t] != -1) ? 1 : 0;
    dg += msk & (int)(st[t] == m);
    dg += msk & (int)(sh[t] == m);
  }
  sscan[tid] = dg;
  __syncthreads();
  for (int off = 1; off < kM; off <<= 1) {
    int add = (tid >= off) ? sscan[tid - off] : 0;
    __syncthreads();
    sscan[tid] += add;
    __syncthreads();
  }
  int excl = sscan[tid] - dg;
  int rs = b * (2 * kT) + excl;
  deg[b * kM + m] = dg;
  rowstart[b * kM + m] = rs;
  int ptr = rs;
  for (int t = 0; t < kT; ++t) {
    if (sl[t] == -1) continue;
    if (st[t] == m) { esrc[ptr] = sh[t]; erel[ptr] = t; ++ptr; }
    if (sh[t] == m) { esrc[ptr] = st[t]; erel[ptr] = t; ++ptr; }
  }
}

// ---------------- U = aggregated messages / max(cnt,1), bf16 in/out ----------------
__global__ __launch_bounds__(128) void compute_upd_k(
    const ushort4* __restrict__ Xbf, const ushort4* __restrict__ Rbf,
    const int* __restrict__ deg, const int* __restrict__ rowstart,
    const int* __restrict__ esrc, const int* __restrict__ erel,
    ushort4* __restrict__ Ubf)
{
  int bm = blockIdx.x;
  int b = bm >> 10;
  int tid = threadIdx.x;  // 128 threads x 4 elems = 512
  int dg = deg[bm];
  int rs = rowstart[bm];
  float ax = 0.f, ay = 0.f, az = 0.f, aw = 0.f;
  size_t xbase = (size_t)b * kM * 128;
  size_t rbase = (size_t)b * kT * 128;
  for (int e = 0; e < dg; ++e) {
    int src = esrc[rs + e];
    int rl = erel[rs + e];
    ushort4 xv = Xbf[xbase + (size_t)src * 128 + tid];
    ushort4 rv = Rbf[rbase + (size_t)rl * 128 + tid];
    ax += bf2f(xv.x) - bf2f(rv.x);
    ay += bf2f(xv.y) - bf2f(rv.y);
    az += bf2f(xv.z) - bf2f(rv.z);
    aw += bf2f(xv.w) - bf2f(rv.w);
  }
  float s = 1.0f / (float)(dg > 0 ? dg : 1);
  ushort4 o;
  o.x = f2bf(ax * s); o.y = f2bf(ay * s); o.z = f2bf(az * s); o.w = f2bf(aw * s);
  Ubf[(size_t)bm * 128 + tid] = o;
}

// ---------------- bf16 MFMA GEMM ----------------
// C[r, e] = sum_k A[r,k] * W[e,k]   (A and W both K-contiguous)
// MODE 0: A = [Xbf | Ubf] (K=1024), W = [Ws|Wn] -> relu -> outbf (X next)
// MODE 1: A = Rbf (K=512), W = Wr -> outbf (REL next)
// MODE 2: A = [Xbf[head] | Rbf | Xbf[tail]] (K=1536), W = Wt (row stride 1536) -> outf
// 128x128 tile, BK=64, 256 threads (4 waves, 2x2 of 64x64), swizzled LDS.
template<int MODE>
__global__ __launch_bounds__(256) void mfma_gemm_k(
    const ushort* __restrict__ Xbf, const ushort* __restrict__ Ubf,
    const ushort* __restrict__ Rbf,
    const ushort* __restrict__ W1, const ushort* __restrict__ W2,
    const int* __restrict__ headp, const int* __restrict__ tailp,
    float* __restrict__ outf, ushort* __restrict__ outbf)
{
  constexpr int NSEG = (MODE == 0) ? 2 : (MODE == 1) ? 1 : 3;
  __shared__ __align__(16) char lds[32768];
  char* ldsA = lds;
  char* ldsB = lds + 16384;
  const int tid = threadIdx.x;
  const int w = tid >> 6;
  const int l = tid & 63;
  const int wr = w >> 1;
  const int wc = w & 1;
  const int bid = blockIdx.x;
  const int rowBase = (bid >> 2) * 128;
  const int colBase = (bid & 3) * 128;

  f4acc acc[4][4];
#pragma unroll
  for (int i = 0; i < 4; ++i)
#pragma unroll
    for (int j = 0; j < 4; ++j) acc[i][j] = (f4acc)(0.f);

  // staging geometry: physical granule P = (i*4+w)*64 + l, row = P>>3,
  // swizzled source column granule gc = (P&7) ^ (row&7)
  int lrow[4], gc[4];
#pragma unroll
  for (int i = 0; i < 4; ++i) {
    int P = (i * 4 + w) * 64 + l;
    lrow[i] = P >> 3;
    gc[i] = (P & 7) ^ (lrow[i] & 7);
  }

  for (int seg = 0; seg < NSEG; ++seg) {
    const char* aP[4];
    const char* bP[4];
#pragma unroll
    for (int i = 0; i < 4; ++i) {
      int grow = rowBase + lrow[i];
      const ushort* ab;
      if constexpr (MODE == 0) {
        ab = (seg == 0 ? Xbf : Ubf) + (size_t)grow * kD;
      } else if constexpr (MODE == 1) {
        ab = Rbf + (size_t)grow * kD;
      } else {
        int bb = grow >> 12;
        if (seg == 0)      ab = Xbf + ((size_t)(bb << 10) + headp[grow]) * kD;
        else if (seg == 1) ab = Rbf + (size_t)grow * kD;
        else               ab = Xbf + ((size_t)(bb << 10) + tailp[grow]) * kD;
      }
      aP[i] = (const char*)ab + gc[i] * 16;
      int e = colBase + lrow[i];
      const ushort* wb;
      if constexpr (MODE == 0) {
        wb = (seg == 0 ? W1 : W2) + (size_t)e * kD;
      } else if constexpr (MODE == 1) {
        wb = W1 + (size_t)e * kD;
      } else {
        wb = W1 + (size_t)e * 1536 + seg * 512;
      }
      bP[i] = (const char*)wb + gc[i] * 16;
    }

    for (int kcl = 0; kcl < 8; ++kcl) {
      __syncthreads();
#pragma unroll
      for (int i = 0; i < 4; ++i) {
        gload_lds16(aP[i] + kcl * 128, ldsA + (i * 4 + w) * 1024);
        gload_lds16(bP[i] + kcl * 128, ldsB + (i * 4 + w) * 1024);
      }
      __syncthreads();
#pragma unroll
      for (int ksub = 0; ksub < 2; ++ksub) {
        bfrag8 af[4], bfv[4];
        int g = (ksub * 4 + (l >> 4)) ^ (l & 7);  // swizzled column granule
#pragma unroll
        for (int mi = 0; mi < 4; ++mi) {
          int r = wr * 64 + mi * 16 + (l & 15);
          af[mi] = *(const bfrag8*)(ldsA + r * 128 + g * 16);
        }
#pragma unroll
        for (int ni = 0; ni < 4; ++ni) {
          int e = wc * 64 + ni * 16 + (l & 15);
          bfv[ni] = *(const bfrag8*)(ldsB + e * 128 + g * 16);
        }
#pragma unroll
        for (int mi = 0; mi < 4; ++mi)
#pragma unroll
          for (int ni = 0; ni < 4; ++ni)
            acc[mi][ni] = __builtin_amdgcn_mfma_f32_16x16x32_bf16(
                af[mi], bfv[ni], acc[mi][ni], 0, 0, 0);
      }
    }
  }

  // epilogue: C/D layout col = lane&15, row = (lane>>4)*4 + q
#pragma unroll
  for (int mi = 0; mi < 4; ++mi) {
#pragma unroll
    for (int ni = 0; ni < 4; ++ni) {
#pragma unroll
      for (int q = 0; q < 4; ++q) {
        int rr = rowBase + wr * 64 + mi * 16 + (l >> 4) * 4 + q;
        int cc = colBase + wc * 64 + ni * 16 + (l & 15);
        float v = acc[mi][ni][q];
        if constexpr (MODE == 0) v = fmaxf(v, 0.f);
        if constexpr (MODE == 2) outf[(size_t)rr * kD + cc] = v;
        else outbf[(size_t)rr * kD + cc] = f2bf(v);
      }
    }
  }
}

// ---------------- encoded_cause reduction (2-pass, deterministic) ----------------
__global__ __launch_bounds__(128) void reduce1_k(
    const float4* __restrict__ outv, float4* __restrict__ part)
{
  int blk = blockIdx.x;
  int b = blk >> 4;
  int c = blk & 15;
  int tid = threadIdx.x;
  float ax = 0.f, ay = 0.f, az = 0.f, aw = 0.f;
  size_t base = ((size_t)b * kT + (size_t)c * 256) * 128;
  for (int t = 0; t < 256; ++t) {
    float4 v = outv[base + (size_t)t * 128 + tid];
    ax += v.x; ay += v.y; az += v.z; aw += v.w;
  }
  float4 o; o.x = ax; o.y = ay; o.z = az; o.w = aw;
  part[(size_t)blk * 128 + tid] = o;
}

__global__ __launch_bounds__(128) void reduce2_k(
    const float4* __restrict__ part, float4* __restrict__ enc)
{
  int b = blockIdx.x;
  int tid = threadIdx.x;
  float ax = 0.f, ay = 0.f, az = 0.f, aw = 0.f;
  for (int c = 0; c < 16; ++c) {
    float4 v = part[((size_t)(b * 16 + c)) * 128 + tid];
    ax += v.x; ay += v.y; az += v.z; aw += v.w;
  }
  float4 o; o.x = ax; o.y = ay; o.z = az; o.w = aw;
  enc[(size_t)b * 128 + tid] = o;
}

}  // namespace

extern "C" void kernel_launch(void* const* d_in, const int* in_sizes, int n_in,
                              void* d_out, int out_size, void* d_ws, size_t ws_size,
                              hipStream_t stream) {
  const float* emb = (const float*)d_in[0];
  const float* Ws = (const float*)d_in[1];
  const float* Wn = (const float*)d_in[2];
  const float* Wr = (const float*)d_in[3];
  const float* Wt = (const float*)d_in[4];
  const int* cid = (const int*)d_in[5];
  const int* relid = (const int*)d_in[6];
  const int* headp = (const int*)d_in[7];
  const int* tailp = (const int*)d_in[8];
  const int* lblp = (const int*)d_in[9];
  float* out = (float*)d_out;

  // ---- workspace layout (bytes) ----
  char* wsp = (char*)d_ws;
  ushort* Xa  = (ushort*)(wsp);                         // 16 MB  (MODE2-read X)
  ushort* R0  = (ushort*)(wsp + (16ull << 20));         // 64 MB  (MODE2-read REL)
  ushort* Wsb = (ushort*)(wsp + (80ull << 20));         // 1 MB (2 hops)
  ushort* Wnb = (ushort*)(wsp + (81ull << 20));         // 1 MB
  ushort* Wrb = (ushort*)(wsp + (82ull << 20));         // 1 MB
  ushort* Wtb = (ushort*)(wsp + (83ull << 20));         // 1.5 MB
  int* deg      = (int*)(wsp + (85ull << 20));
  int* rowstart = deg + kB * kM;
  int* esrc     = rowstart + kB * kM;
  int* erel     = esrc + kB * 2 * kT;
  float* part   = (float*)(wsp + (87ull << 20));        // 0.5 MB

  // ---- d_out region doubles as hop-intermediate scratch (dead before MODE2) ----
  char* outc = (char*)d_out;
  ushort* R1 = (ushort*)(outc);                  // 64 MB
  ushort* Ub = (ushort*)(outc + (64ull << 20));  // 16 MB
  ushort* Xb = (ushort*)(outc + (80ull << 20));  // 16 MB (ends at 96 MB < 128 MB)
  float* ENC = out + (size_t)kB * kT * kD;

  // weights -> bf16
  cvt_bf16_k<<<512, 256, 0, stream>>>((const float4*)Ws, (ushort4*)Wsb, 2 * kD * kD / 4);
  cvt_bf16_k<<<512, 256, 0, stream>>>((const float4*)Wn, (ushort4*)Wnb, 2 * kD * kD / 4);
  cvt_bf16_k<<<512, 256, 0, stream>>>((const float4*)Wr, (ushort4*)Wrb, 2 * kD * kD / 4);
  cvt_bf16_k<<<768, 256, 0, stream>>>((const float4*)Wt, (ushort4*)Wtb, kD * 1536 / 4);

  // gather embeddings -> bf16
  gather_bf16_k<<<(kB * kM * 128) / 256, 256, 0, stream>>>(
      (const float4*)emb, cid, (ushort4*)Xa, kB * kM);
  gather_bf16_k<<<(kB * kT * 128) / 256, 256, 0, stream>>>(
      (const float4*)emb, relid, (ushort4*)R0, kB * kT);

  build_csr_k<<<kB, 1024, 0, stream>>>(headp, tailp, lblp, deg, rowstart, esrc, erel);

  ushort* Xcur = Xa; ushort* Xnxt = Xb;
  ushort* Rcur = R0; ushort* Rnxt = R1;
  for (int h = 0; h < 2; ++h) {
    compute_upd_k<<<kB * kM, 128, 0, stream>>>(
        (const ushort4*)Xcur, (const ushort4*)Rcur, deg, rowstart, esrc, erel,
        (ushort4*)Ub);
    mfma_gemm_k<0><<<(kB * kM / 128) * 4, 256, 0, stream>>>(
        Xcur, Ub, nullptr, Wsb + (size_t)h * kD * kD, Wnb + (size_t)h * kD * kD,
        nullptr, nullptr, nullptr, Xnxt);
    mfma_gemm_k<1><<<(kB * kT / 128) * 4, 256, 0, stream>>>(
        nullptr, nullptr, Rcur, Wrb + (size_t)h * kD * kD, nullptr,
        nullptr, nullptr, nullptr, Rnxt);
    ushort* t;
    t = Xcur; Xcur = Xnxt; Xnxt = t;
    t = Rcur; Rcur = Rnxt; Rnxt = t;
  }

  // final triple GEMM: reads Xa/R0 (ws), writes fp32 out
  mfma_gemm_k<2><<<(kB * kT / 128) * 4, 256, 0, stream>>>(
      Xcur, nullptr, Rcur, Wtb, nullptr, headp, tailp, out, nullptr);

  reduce1_k<<<kB * 16, 128, 0, stream>>>((const float4*)out, (float4*)part);
  reduce2_k<<<kB, 128, 0, stream>>>((const float4*)part, (float4*)ENC);
}

// Round 3
// 435.334 us; speedup vs baseline: 7.7320x; 2.4592x over previous
//
#include <hip/hip_runtime.h>

namespace {

constexpr int kB = 16;
constexpr int kM = 1024;
constexpr int kT = 4096;
constexpr int kD = 512;

typedef __attribute__((ext_vector_type(8))) short bfrag8;
typedef __attribute__((ext_vector_type(4))) float f4acc;

__device__ __forceinline__ ushort f2bf(float f) {
  unsigned u = __float_as_uint(f);
  u += 0x7fffu + ((u >> 16) & 1u);
  return (ushort)(u >> 16);
}
__device__ __forceinline__ float bf2f(ushort h) {
  return __uint_as_float(((unsigned)h) << 16);
}

__device__ __forceinline__ void gload_lds16(const void* g, void* l) {
  __builtin_amdgcn_global_load_lds(
      (const __attribute__((address_space(1))) void*)g,
      (__attribute__((address_space(3))) void*)l, 16, 0, 0);
}

// ---------------- fp32 -> bf16 conversion (weights) ----------------
__global__ __launch_bounds__(256) void cvt_bf16_k(
    const float4* __restrict__ in, ushort4* __restrict__ out, int n4)
{
  int i = blockIdx.x * 256 + threadIdx.x;
  if (i >= n4) return;
  float4 v = in[i];
  ushort4 o;
  o.x = f2bf(v.x); o.y = f2bf(v.y); o.z = f2bf(v.z); o.w = f2bf(v.w);
  out[i] = o;
}

// ---------------- gather emb rows -> bf16 ----------------
__global__ __launch_bounds__(256) void gather_bf16_k(
    const float4* __restrict__ embv, const int* __restrict__ ids,
    ushort4* __restrict__ outv, int nrows)
{
  int i = blockIdx.x * 256 + threadIdx.x;
  if (i >= nrows * 128) return;
  int row = i >> 7;
  int c = i & 127;
  int id = ids[row];
  float4 v = embv[(size_t)id * 128 + c];
  ushort4 o;
  o.x = f2bf(v.x); o.y = f2bf(v.y); o.z = f2bf(v.z); o.w = f2bf(v.w);
  outv[i] = o;
}

// ---------------- CSR build, O(T) atomic counting-sort (deterministic) ----------
__global__ __launch_bounds__(256) void zero_k(int* __restrict__ p, int n) {
  int i = blockIdx.x * 256 + threadIdx.x;
  if (i < n) p[i] = 0;
}

__global__ __launch_bounds__(256) void deg_count_k(
    const int* __restrict__ headp, const int* __restrict__ tailp,
    const int* __restrict__ lblp, int* __restrict__ deg)
{
  int i = blockIdx.x * 256 + threadIdx.x;  // 0..B*T
  if (i >= kB * kT) return;
  if (lblp[i] == -1) return;
  int b = i >> 12;
  atomicAdd(&deg[(b << 10) + tailp[i]], 1);
  atomicAdd(&deg[(b << 10) + headp[i]], 1);
}

__global__ __launch_bounds__(1024) void scan_k(
    const int* __restrict__ deg, int* __restrict__ rowstart,
    int* __restrict__ fillptr)
{
  __shared__ int s[kM];
  int b = blockIdx.x;
  int tid = threadIdx.x;
  int d = deg[b * kM + tid];
  s[tid] = d;
  __syncthreads();
  for (int off = 1; off < kM; off <<= 1) {
    int add = (tid >= off) ? s[tid - off] : 0;
    __syncthreads();
    s[tid] += add;
    __syncthreads();
  }
  int rs = b * (2 * kT) + s[tid] - d;
  rowstart[b * kM + tid] = rs;
  fillptr[b * kM + tid] = rs;
}

// pack: (seq = 2t + isHeadEntry) << 10 | src   (seq<=8191: 13b, src<=1023: 10b)
__global__ __launch_bounds__(256) void fill_k(
    const int* __restrict__ headp, const int* __restrict__ tailp,
    const int* __restrict__ lblp, int* __restrict__ fillptr,
    int* __restrict__ epack)
{
  int i = blockIdx.x * 256 + threadIdx.x;
  if (i >= kB * kT) return;
  if (lblp[i] == -1) return;
  int b = i >> 12;
  int t = i & (kT - 1);
  int hd = headp[i];
  int tl = tailp[i];
  int p0 = atomicAdd(&fillptr[(b << 10) + tl], 1);
  epack[p0] = ((t * 2) << 10) | hd;
  int p1 = atomicAdd(&fillptr[(b << 10) + hd], 1);
  epack[p1] = ((t * 2 + 1) << 10) | tl;
}

// per-node insertion sort by packed key -> exact reference order, deterministic
__global__ __launch_bounds__(256) void sort_k(
    const int* __restrict__ rowstart, const int* __restrict__ deg,
    int* __restrict__ epack)
{
  int bm = blockIdx.x * 256 + threadIdx.x;
  if (bm >= kB * kM) return;
  int rs = rowstart[bm];
  int dg = deg[bm];
  for (int i = 1; i < dg; ++i) {
    int key = epack[rs + i];
    int j = i - 1;
    while (j >= 0 && epack[rs + j] > key) {
      epack[rs + j + 1] = epack[rs + j];
      --j;
    }
    epack[rs + j + 1] = key;
  }
}

// ---------------- U = aggregated messages / max(cnt,1), bf16 in/out ----------------
__global__ __launch_bounds__(128) void compute_upd_k(
    const ushort4* __restrict__ Xbf, const ushort4* __restrict__ Rbf,
    const int* __restrict__ deg, const int* __restrict__ rowstart,
    const int* __restrict__ epack,
    ushort4* __restrict__ Ubf)
{
  int bm = blockIdx.x;
  int b = bm >> 10;
  int tid = threadIdx.x;  // 128 threads x 4 elems = 512
  int dg = deg[bm];
  int rs = rowstart[bm];
  float ax = 0.f, ay = 0.f, az = 0.f, aw = 0.f;
  size_t xbase = (size_t)b * kM * 128;
  size_t rbase = (size_t)b * kT * 128;
  for (int e = 0; e < dg; ++e) {
    int pk = epack[rs + e];
    int src = pk & 1023;
    int rl = pk >> 11;
    ushort4 xv = Xbf[xbase + (size_t)src * 128 + tid];
    ushort4 rv = Rbf[rbase + (size_t)rl * 128 + tid];
    ax += bf2f(xv.x) - bf2f(rv.x);
    ay += bf2f(xv.y) - bf2f(rv.y);
    az += bf2f(xv.z) - bf2f(rv.z);
    aw += bf2f(xv.w) - bf2f(rv.w);
  }
  float s = 1.0f / (float)(dg > 0 ? dg : 1);
  ushort4 o;
  o.x = f2bf(ax * s); o.y = f2bf(ay * s); o.z = f2bf(az * s); o.w = f2bf(aw * s);
  Ubf[(size_t)bm * 128 + tid] = o;
}

// ---------------- bf16 MFMA GEMM ----------------
// C[r, e] = sum_k A[r,k] * W[e,k]   (A and W both K-contiguous)
// MODE 0: A = [Xbf | Ubf] (K=1024), W = [Ws|Wn] -> relu -> outbf (X next)
// MODE 1: A = Rbf (K=512), W = Wr -> outbf (REL next)
// MODE 2: A = [Xbf[head] | Rbf | Xbf[tail]] (K=1536), W = Wt (row stride 1536) -> outf
// 128x128 tile, BK=64, 256 threads (4 waves, 2x2 of 64x64), swizzled LDS.
template<int MODE>
__global__ __launch_bounds__(256) void mfma_gemm_k(
    const ushort* __restrict__ Xbf, const ushort* __restrict__ Ubf,
    const ushort* __restrict__ Rbf,
    const ushort* __restrict__ W1, const ushort* __restrict__ W2,
    const int* __restrict__ headp, const int* __restrict__ tailp,
    float* __restrict__ outf, ushort* __restrict__ outbf)
{
  constexpr int NSEG = (MODE == 0) ? 2 : (MODE == 1) ? 1 : 3;
  __shared__ __align__(16) char lds[32768];
  char* ldsA = lds;
  char* ldsB = lds + 16384;
  const int tid = threadIdx.x;
  const int w = tid >> 6;
  const int l = tid & 63;
  const int wr = w >> 1;
  const int wc = w & 1;
  const int bid = blockIdx.x;
  const int rowBase = (bid >> 2) * 128;
  const int colBase = (bid & 3) * 128;

  f4acc acc[4][4];
#pragma unroll
  for (int i = 0; i < 4; ++i)
#pragma unroll
    for (int j = 0; j < 4; ++j) acc[i][j] = (f4acc)(0.f);

  // staging geometry: physical granule P = (i*4+w)*64 + l, row = P>>3,
  // swizzled source column granule gc = (P&7) ^ (row&7)
  int lrow[4], gc[4];
#pragma unroll
  for (int i = 0; i < 4; ++i) {
    int P = (i * 4 + w) * 64 + l;
    lrow[i] = P >> 3;
    gc[i] = (P & 7) ^ (lrow[i] & 7);
  }

  for (int seg = 0; seg < NSEG; ++seg) {
    const char* aP[4];
    const char* bP[4];
#pragma unroll
    for (int i = 0; i < 4; ++i) {
      int grow = rowBase + lrow[i];
      const ushort* ab;
      if constexpr (MODE == 0) {
        ab = (seg == 0 ? Xbf : Ubf) + (size_t)grow * kD;
      } else if constexpr (MODE == 1) {
        ab = Rbf + (size_t)grow * kD;
      } else {
        int bb = grow >> 12;
        if (seg == 0)      ab = Xbf + ((size_t)(bb << 10) + headp[grow]) * kD;
        else if (seg == 1) ab = Rbf + (size_t)grow * kD;
        else               ab = Xbf + ((size_t)(bb << 10) + tailp[grow]) * kD;
      }
      aP[i] = (const char*)ab + gc[i] * 16;
      int e = colBase + lrow[i];
      const ushort* wb;
      if constexpr (MODE == 0) {
        wb = (seg == 0 ? W1 : W2) + (size_t)e * kD;
      } else if constexpr (MODE == 1) {
        wb = W1 + (size_t)e * kD;
      } else {
        wb = W1 + (size_t)e * 1536 + seg * 512;
      }
      bP[i] = (const char*)wb + gc[i] * 16;
    }

    for (int kcl = 0; kcl < 8; ++kcl) {
      __syncthreads();
#pragma unroll
      for (int i = 0; i < 4; ++i) {
        gload_lds16(aP[i] + kcl * 128, ldsA + (i * 4 + w) * 1024);
        gload_lds16(bP[i] + kcl * 128, ldsB + (i * 4 + w) * 1024);
      }
      __syncthreads();
#pragma unroll
      for (int ksub = 0; ksub < 2; ++ksub) {
        bfrag8 af[4], bfv[4];
        int g = (ksub * 4 + (l >> 4)) ^ (l & 7);  // swizzled column granule
#pragma unroll
        for (int mi = 0; mi < 4; ++mi) {
          int r = wr * 64 + mi * 16 + (l & 15);
          af[mi] = *(const bfrag8*)(ldsA + r * 128 + g * 16);
        }
#pragma unroll
        for (int ni = 0; ni < 4; ++ni) {
          int e = wc * 64 + ni * 16 + (l & 15);
          bfv[ni] = *(const bfrag8*)(ldsB + e * 128 + g * 16);
        }
#pragma unroll
        for (int mi = 0; mi < 4; ++mi)
#pragma unroll
          for (int ni = 0; ni < 4; ++ni)
            acc[mi][ni] = __builtin_amdgcn_mfma_f32_16x16x32_bf16(
                af[mi], bfv[ni], acc[mi][ni], 0, 0, 0);
      }
    }
  }

  // epilogue: C/D layout col = lane&15, row = (lane>>4)*4 + q
#pragma unroll
  for (int mi = 0; mi < 4; ++mi) {
#pragma unroll
    for (int ni = 0; ni < 4; ++ni) {
#pragma unroll
      for (int q = 0; q < 4; ++q) {
        int rr = rowBase + wr * 64 + mi * 16 + (l >> 4) * 4 + q;
        int cc = colBase + wc * 64 + ni * 16 + (l & 15);
        float v = acc[mi][ni][q];
        if constexpr (MODE == 0) v = fmaxf(v, 0.f);
        if constexpr (MODE == 2) outf[(size_t)rr * kD + cc] = v;
        else outbf[(size_t)rr * kD + cc] = f2bf(v);
      }
    }
  }
}

// ---------------- encoded_cause reduction (2-pass, deterministic) ----------------
__global__ __launch_bounds__(128) void reduce1_k(
    const float4* __restrict__ outv, float4* __restrict__ part)
{
  int blk = blockIdx.x;
  int b = blk >> 4;
  int c = blk & 15;
  int tid = threadIdx.x;
  float ax = 0.f, ay = 0.f, az = 0.f, aw = 0.f;
  size_t base = ((size_t)b * kT + (size_t)c * 256) * 128;
  for (int t = 0; t < 256; ++t) {
    float4 v = outv[base + (size_t)t * 128 + tid];
    ax += v.x; ay += v.y; az += v.z; aw += v.w;
  }
  float4 o; o.x = ax; o.y = ay; o.z = az; o.w = aw;
  part[(size_t)blk * 128 + tid] = o;
}

__global__ __launch_bounds__(128) void reduce2_k(
    const float4* __restrict__ part, float4* __restrict__ enc)
{
  int b = blockIdx.x;
  int tid = threadIdx.x;
  float ax = 0.f, ay = 0.f, az = 0.f, aw = 0.f;
  for (int c = 0; c < 16; ++c) {
    float4 v = part[((size_t)(b * 16 + c)) * 128 + tid];
    ax += v.x; ay += v.y; az += v.z; aw += v.w;
  }
  float4 o; o.x = ax; o.y = ay; o.z = az; o.w = aw;
  enc[(size_t)b * 128 + tid] = o;
}

}  // namespace

extern "C" void kernel_launch(void* const* d_in, const int* in_sizes, int n_in,
                              void* d_out, int out_size, void* d_ws, size_t ws_size,
                              hipStream_t stream) {
  const float* emb = (const float*)d_in[0];
  const float* Ws = (const float*)d_in[1];
  const float* Wn = (const float*)d_in[2];
  const float* Wr = (const float*)d_in[3];
  const float* Wt = (const float*)d_in[4];
  const int* cid = (const int*)d_in[5];
  const int* relid = (const int*)d_in[6];
  const int* headp = (const int*)d_in[7];
  const int* tailp = (const int*)d_in[8];
  const int* lblp = (const int*)d_in[9];
  float* out = (float*)d_out;

  // ---- workspace layout (bytes) ----
  char* wsp = (char*)d_ws;
  ushort* Xa  = (ushort*)(wsp);                         // 16 MB  (MODE2-read X)
  ushort* R0  = (ushort*)(wsp + (16ull << 20));         // 64 MB  (MODE2-read REL)
  ushort* Wsb = (ushort*)(wsp + (80ull << 20));         // 1 MB (2 hops)
  ushort* Wnb = (ushort*)(wsp + (81ull << 20));         // 1 MB
  ushort* Wrb = (ushort*)(wsp + (82ull << 20));         // 1 MB
  ushort* Wtb = (ushort*)(wsp + (83ull << 20));         // 1.5 MB
  int* deg      = (int*)(wsp + (85ull << 20));          // 64 KB
  int* rowstart = deg + kB * kM;                        // 64 KB
  int* fillptr  = rowstart + kB * kM;                   // 64 KB
  int* epack    = fillptr + kB * kM;                    // 512 KB
  float* part   = (float*)(wsp + (87ull << 20));        // 0.5 MB

  // ---- d_out region doubles as hop-intermediate scratch (dead before MODE2) ----
  char* outc = (char*)d_out;
  ushort* R1 = (ushort*)(outc);                  // 64 MB
  ushort* Ub = (ushort*)(outc + (64ull << 20));  // 16 MB
  ushort* Xb = (ushort*)(outc + (80ull << 20));  // 16 MB (ends at 96 MB < 128 MB)
  float* ENC = out + (size_t)kB * kT * kD;

  // weights -> bf16
  cvt_bf16_k<<<512, 256, 0, stream>>>((const float4*)Ws, (ushort4*)Wsb, 2 * kD * kD / 4);
  cvt_bf16_k<<<512, 256, 0, stream>>>((const float4*)Wn, (ushort4*)Wnb, 2 * kD * kD / 4);
  cvt_bf16_k<<<512, 256, 0, stream>>>((const float4*)Wr, (ushort4*)Wrb, 2 * kD * kD / 4);
  cvt_bf16_k<<<768, 256, 0, stream>>>((const float4*)Wt, (ushort4*)Wtb, kD * 1536 / 4);

  // gather embeddings -> bf16
  gather_bf16_k<<<(kB * kM * 128) / 256, 256, 0, stream>>>(
      (const float4*)emb, cid, (ushort4*)Xa, kB * kM);
  gather_bf16_k<<<(kB * kT * 128) / 256, 256, 0, stream>>>(
      (const float4*)emb, relid, (ushort4*)R0, kB * kT);

  // CSR build: zero -> count -> scan -> fill -> per-node sort (deterministic)
  zero_k<<<(kB * kM + 255) / 256, 256, 0, stream>>>(deg, kB * kM);
  deg_count_k<<<(kB * kT + 255) / 256, 256, 0, stream>>>(headp, tailp, lblp, deg);
  scan_k<<<kB, 1024, 0, stream>>>(deg, rowstart, fillptr);
  fill_k<<<(kB * kT + 255) / 256, 256, 0, stream>>>(headp, tailp, lblp, fillptr, epack);
  sort_k<<<(kB * kM + 255) / 256, 256, 0, stream>>>(rowstart, deg, epack);

  ushort* Xcur = Xa; ushort* Xnxt = Xb;
  ushort* Rcur = R0; ushort* Rnxt = R1;
  for (int h = 0; h < 2; ++h) {
    compute_upd_k<<<kB * kM, 128, 0, stream>>>(
        (const ushort4*)Xcur, (const ushort4*)Rcur, deg, rowstart, epack,
        (ushort4*)Ub);
    mfma_gemm_k<0><<<(kB * kM / 128) * 4, 256, 0, stream>>>(
        Xcur, Ub, nullptr, Wsb + (size_t)h * kD * kD, Wnb + (size_t)h * kD * kD,
        nullptr, nullptr, nullptr, Xnxt);
    mfma_gemm_k<1><<<(kB * kT / 128) * 4, 256, 0, stream>>>(
        nullptr, nullptr, Rcur, Wrb + (size_t)h * kD * kD, nullptr,
        nullptr, nullptr, nullptr, Rnxt);
    ushort* t;
    t = Xcur; Xcur = Xnxt; Xnxt = t;
    t = Rcur; Rcur = Rnxt; Rnxt = t;
  }

  // final triple GEMM: reads X/REL, writes fp32 out
  mfma_gemm_k<2><<<(kB * kT / 128) * 4, 256, 0, stream>>>(
      Xcur, nullptr, Rcur, Wtb, nullptr, headp, tailp, out, nullptr);

  reduce1_k<<<kB * 16, 128, 0, stream>>>((const float4*)out, (float4*)part);
  reduce2_k<<<kB, 128, 0, stream>>>((const float4*)part, (float4*)ENC);
}

// Round 4
// 405.667 us; speedup vs baseline: 8.2975x; 1.0731x over previous
//
#include <hip/hip_runtime.h>

namespace {

constexpr int kB = 16;
constexpr int kM = 1024;
constexpr int kT = 4096;
constexpr int kD = 512;

typedef __attribute__((ext_vector_type(8))) short bfrag8;
typedef __attribute__((ext_vector_type(4))) float f4acc;

__device__ __forceinline__ ushort f2bf(float f) {
  unsigned u = __float_as_uint(f);
  u += 0x7fffu + ((u >> 16) & 1u);
  return (ushort)(u >> 16);
}
__device__ __forceinline__ float bf2f(ushort h) {
  return __uint_as_float(((unsigned)h) << 16);
}

__device__ __forceinline__ void gload_lds16(const void* g, void* l) {
  __builtin_amdgcn_global_load_lds(
      (const __attribute__((address_space(1))) void*)g,
      (__attribute__((address_space(3))) void*)l, 16, 0, 0);
}

// ---------------- fp32 -> bf16 conversion (weights) ----------------
__global__ __launch_bounds__(256) void cvt_bf16_k(
    const float4* __restrict__ in, ushort4* __restrict__ out, int n4)
{
  int i = blockIdx.x * 256 + threadIdx.x;
  if (i >= n4) return;
  float4 v = in[i];
  ushort4 o;
  o.x = f2bf(v.x); o.y = f2bf(v.y); o.z = f2bf(v.z); o.w = f2bf(v.w);
  out[i] = o;
}

// ---------------- Wcomb[d,k] = sum_e Wr2[e,k] * Wt[d, 512+e]  (fp32 -> bf16) ----
__global__ __launch_bounds__(512) void wcomb_k(
    const float* __restrict__ Wr2, const float* __restrict__ Wt,
    ushort* __restrict__ Wcb)
{
  __shared__ float wrow[4][512];
  int d0 = blockIdx.x * 4;  // 128 blocks
  int k = threadIdx.x;
#pragma unroll
  for (int i = 0; i < 4; ++i)
    wrow[i][k] = Wt[(size_t)(d0 + i) * 1536 + 512 + k];
  __syncthreads();
  float acc[4] = {0.f, 0.f, 0.f, 0.f};
  for (int e = 0; e < 512; ++e) {
    float wv = Wr2[e * 512 + k];
#pragma unroll
    for (int i = 0; i < 4; ++i) acc[i] = fmaf(wv, wrow[i][e], acc[i]);
  }
#pragma unroll
  for (int i = 0; i < 4; ++i) Wcb[(d0 + i) * 512 + k] = f2bf(acc[i]);
}

// ---------------- gather emb rows -> bf16 ----------------
__global__ __launch_bounds__(256) void gather_bf16_k(
    const float4* __restrict__ embv, const int* __restrict__ ids,
    ushort4* __restrict__ outv, int nrows)
{
  int i = blockIdx.x * 256 + threadIdx.x;
  if (i >= nrows * 128) return;
  int row = i >> 7;
  int c = i & 127;
  int id = ids[row];
  float4 v = embv[(size_t)id * 128 + c];
  ushort4 o;
  o.x = f2bf(v.x); o.y = f2bf(v.y); o.z = f2bf(v.z); o.w = f2bf(v.w);
  outv[i] = o;
}

// ---------------- CSR build, O(T) atomic counting-sort (deterministic) ----------
__global__ __launch_bounds__(256) void zero_k(int* __restrict__ p, int n) {
  int i = blockIdx.x * 256 + threadIdx.x;
  if (i < n) p[i] = 0;
}

__global__ __launch_bounds__(256) void deg_count_k(
    const int* __restrict__ headp, const int* __restrict__ tailp,
    const int* __restrict__ lblp, int* __restrict__ deg)
{
  int i = blockIdx.x * 256 + threadIdx.x;  // 0..B*T
  if (i >= kB * kT) return;
  if (lblp[i] == -1) return;
  int b = i >> 12;
  atomicAdd(&deg[(b << 10) + tailp[i]], 1);
  atomicAdd(&deg[(b << 10) + headp[i]], 1);
}

__global__ __launch_bounds__(1024) void scan_k(
    const int* __restrict__ deg, int* __restrict__ rowstart,
    int* __restrict__ fillptr)
{
  __shared__ int s[kM];
  int b = blockIdx.x;
  int tid = threadIdx.x;
  int d = deg[b * kM + tid];
  s[tid] = d;
  __syncthreads();
  for (int off = 1; off < kM; off <<= 1) {
    int add = (tid >= off) ? s[tid - off] : 0;
    __syncthreads();
    s[tid] += add;
    __syncthreads();
  }
  int rs = b * (2 * kT) + s[tid] - d;
  rowstart[b * kM + tid] = rs;
  fillptr[b * kM + tid] = rs;
}

// pack: (seq = 2t + isHeadEntry) << 10 | src   (seq<=8191: 13b, src<=1023: 10b)
__global__ __launch_bounds__(256) void fill_k(
    const int* __restrict__ headp, const int* __restrict__ tailp,
    const int* __restrict__ lblp, int* __restrict__ fillptr,
    int* __restrict__ epack)
{
  int i = blockIdx.x * 256 + threadIdx.x;
  if (i >= kB * kT) return;
  if (lblp[i] == -1) return;
  int b = i >> 12;
  int t = i & (kT - 1);
  int hd = headp[i];
  int tl = tailp[i];
  int p0 = atomicAdd(&fillptr[(b << 10) + tl], 1);
  epack[p0] = ((t * 2) << 10) | hd;
  int p1 = atomicAdd(&fillptr[(b << 10) + hd], 1);
  epack[p1] = ((t * 2 + 1) << 10) | tl;
}

// per-node insertion sort by packed key -> exact reference order, deterministic
__global__ __launch_bounds__(256) void sort_k(
    const int* __restrict__ rowstart, const int* __restrict__ deg,
    int* __restrict__ epack)
{
  int bm = blockIdx.x * 256 + threadIdx.x;
  if (bm >= kB * kM) return;
  int rs = rowstart[bm];
  int dg = deg[bm];
  for (int i = 1; i < dg; ++i) {
    int key = epack[rs + i];
    int j = i - 1;
    while (j >= 0 && epack[rs + j] > key) {
      epack[rs + j + 1] = epack[rs + j];
      --j;
    }
    epack[rs + j + 1] = key;
  }
}

// ---------------- U = aggregated messages / max(cnt,1), bf16 in/out ----------------
__global__ __launch_bounds__(128) void compute_upd_k(
    const ushort4* __restrict__ Xbf, const ushort4* __restrict__ Rbf,
    const int* __restrict__ deg, const int* __restrict__ rowstart,
    const int* __restrict__ epack,
    ushort4* __restrict__ Ubf)
{
  int bm = blockIdx.x;
  int b = bm >> 10;
  int tid = threadIdx.x;  // 128 threads x 4 elems = 512
  int dg = deg[bm];
  int rs = rowstart[bm];
  float ax = 0.f, ay = 0.f, az = 0.f, aw = 0.f;
  size_t xbase = (size_t)b * kM * 128;
  size_t rbase = (size_t)b * kT * 128;
  for (int e = 0; e < dg; ++e) {
    int pk = epack[rs + e];
    int src = pk & 1023;
    int rl = pk >> 11;
    ushort4 xv = Xbf[xbase + (size_t)src * 128 + tid];
    ushort4 rv = Rbf[rbase + (size_t)rl * 128 + tid];
    ax += bf2f(xv.x) - bf2f(rv.x);
    ay += bf2f(xv.y) - bf2f(rv.y);
    az += bf2f(xv.z) - bf2f(rv.z);
    aw += bf2f(xv.w) - bf2f(rv.w);
  }
  float s = 1.0f / (float)(dg > 0 ? dg : 1);
  ushort4 o;
  o.x = f2bf(ax * s); o.y = f2bf(ay * s); o.z = f2bf(az * s); o.w = f2bf(aw * s);
  Ubf[(size_t)bm * 128 + tid] = o;
}

// ---------------- bf16 MFMA GEMM ----------------
// C[r, e] = sum_k A[r,k] * W[e,k]   (A and W both K-contiguous)
// MODE 0: A = [Xbf | Ubf] (K=1024), W = [Ws|Wn] -> relu -> outbf
// MODE 1: A = Rbf (K=512), W = Wr -> outbf
// MODE 2: A = [Xbf[head] | Rbf | Xbf[tail]] (K=1536),
//         W = [Wt1 (stride 1536) | Wcomb (stride 512) | Wt3 (stride 1536)] -> outf
// 128x128 tile, BK=64, 256 threads (4 waves, 2x2 of 64x64), swizzled LDS.
// Block mapping: XCD panel-grouped — a panel's 4 col-blocks land on one XCD (L2 reuse).
template<int MODE>
__global__ __launch_bounds__(256) void mfma_gemm_k(
    const ushort* __restrict__ Xbf, const ushort* __restrict__ Ubf,
    const ushort* __restrict__ Rbf,
    const ushort* __restrict__ W1, const ushort* __restrict__ W2,
    const int* __restrict__ headp, const int* __restrict__ tailp,
    float* __restrict__ outf, ushort* __restrict__ outbf)
{
  constexpr int NSEG = (MODE == 0) ? 2 : (MODE == 1) ? 1 : 3;
  __shared__ __align__(16) char lds[32768];
  char* ldsA = lds;
  char* ldsB = lds + 16384;
  const int tid = threadIdx.x;
  const int w = tid >> 6;
  const int l = tid & 63;
  const int wr = w >> 1;
  const int wc = w & 1;
  // XCD panel-grouped swizzle (requires npanels % 8 == 0)
  const int bid = blockIdx.x;
  const int ppx = gridDim.x >> 5;  // npanels / 8
  const int panel = (bid & 7) * ppx + ((bid >> 3) >> 2);
  const int rowBase = panel * 128;
  const int colBase = ((bid >> 3) & 3) * 128;

  f4acc acc[4][4];
#pragma unroll
  for (int i = 0; i < 4; ++i)
#pragma unroll
    for (int j = 0; j < 4; ++j) acc[i][j] = (f4acc)(0.f);

  // staging geometry: physical granule P = (i*4+w)*64 + l, row = P>>3,
  // swizzled source column granule gc = (P&7) ^ (row&7)
  int lrow[4], gc[4];
#pragma unroll
  for (int i = 0; i < 4; ++i) {
    int P = (i * 4 + w) * 64 + l;
    lrow[i] = P >> 3;
    gc[i] = (P & 7) ^ (lrow[i] & 7);
  }

  for (int seg = 0; seg < NSEG; ++seg) {
    const char* aP[4];
    const char* bP[4];
#pragma unroll
    for (int i = 0; i < 4; ++i) {
      int grow = rowBase + lrow[i];
      const ushort* ab;
      if constexpr (MODE == 0) {
        ab = (seg == 0 ? Xbf : Ubf) + (size_t)grow * kD;
      } else if constexpr (MODE == 1) {
        ab = Rbf + (size_t)grow * kD;
      } else {
        int bb = grow >> 12;
        if (seg == 0)      ab = Xbf + ((size_t)(bb << 10) + headp[grow]) * kD;
        else if (seg == 1) ab = Rbf + (size_t)grow * kD;
        else               ab = Xbf + ((size_t)(bb << 10) + tailp[grow]) * kD;
      }
      aP[i] = (const char*)ab + gc[i] * 16;
      int e = colBase + lrow[i];
      const ushort* wb;
      if constexpr (MODE == 0) {
        wb = (seg == 0 ? W1 : W2) + (size_t)e * kD;
      } else if constexpr (MODE == 1) {
        wb = W1 + (size_t)e * kD;
      } else {
        wb = (seg == 1) ? (W2 + (size_t)e * 512)
                        : (W1 + (size_t)e * 1536 + (seg == 0 ? 0 : 1024));
      }
      bP[i] = (const char*)wb + gc[i] * 16;
    }

    for (int kcl = 0; kcl < 8; ++kcl) {
      __syncthreads();
#pragma unroll
      for (int i = 0; i < 4; ++i) {
        gload_lds16(aP[i] + kcl * 128, ldsA + (i * 4 + w) * 1024);
        gload_lds16(bP[i] + kcl * 128, ldsB + (i * 4 + w) * 1024);
      }
      __syncthreads();
#pragma unroll
      for (int ksub = 0; ksub < 2; ++ksub) {
        bfrag8 af[4], bfv[4];
        int g = (ksub * 4 + (l >> 4)) ^ (l & 7);  // swizzled column granule
#pragma unroll
        for (int mi = 0; mi < 4; ++mi) {
          int r = wr * 64 + mi * 16 + (l & 15);
          af[mi] = *(const bfrag8*)(ldsA + r * 128 + g * 16);
        }
#pragma unroll
        for (int ni = 0; ni < 4; ++ni) {
          int e = wc * 64 + ni * 16 + (l & 15);
          bfv[ni] = *(const bfrag8*)(ldsB + e * 128 + g * 16);
        }
#pragma unroll
        for (int mi = 0; mi < 4; ++mi)
#pragma unroll
          for (int ni = 0; ni < 4; ++ni)
            acc[mi][ni] = __builtin_amdgcn_mfma_f32_16x16x32_bf16(
                af[mi], bfv[ni], acc[mi][ni], 0, 0, 0);
      }
    }
  }

  // epilogue: C/D layout col = lane&15, row = (lane>>4)*4 + q
#pragma unroll
  for (int mi = 0; mi < 4; ++mi) {
#pragma unroll
    for (int ni = 0; ni < 4; ++ni) {
#pragma unroll
      for (int q = 0; q < 4; ++q) {
        int rr = rowBase + wr * 64 + mi * 16 + (l >> 4) * 4 + q;
        int cc = colBase + wc * 64 + ni * 16 + (l & 15);
        float v = acc[mi][ni][q];
        if constexpr (MODE == 0) v = fmaxf(v, 0.f);
        if constexpr (MODE == 2) outf[(size_t)rr * kD + cc] = v;
        else outbf[(size_t)rr * kD + cc] = f2bf(v);
      }
    }
  }
}

// ---------------- encoded_cause reduction (2-pass, deterministic) ----------------
__global__ __launch_bounds__(128) void reduce1_k(
    const float4* __restrict__ outv, float4* __restrict__ part)
{
  int blk = blockIdx.x;
  int b = blk >> 4;
  int c = blk & 15;
  int tid = threadIdx.x;
  float ax = 0.f, ay = 0.f, az = 0.f, aw = 0.f;
  size_t base = ((size_t)b * kT + (size_t)c * 256) * 128;
  for (int t = 0; t < 256; ++t) {
    float4 v = outv[base + (size_t)t * 128 + tid];
    ax += v.x; ay += v.y; az += v.z; aw += v.w;
  }
  float4 o; o.x = ax; o.y = ay; o.z = az; o.w = aw;
  part[(size_t)blk * 128 + tid] = o;
}

__global__ __launch_bounds__(128) void reduce2_k(
    const float4* __restrict__ part, float4* __restrict__ enc)
{
  int b = blockIdx.x;
  int tid = threadIdx.x;
  float ax = 0.f, ay = 0.f, az = 0.f, aw = 0.f;
  for (int c = 0; c < 16; ++c) {
    float4 v = part[((size_t)(b * 16 + c)) * 128 + tid];
    ax += v.x; ay += v.y; az += v.z; aw += v.w;
  }
  float4 o; o.x = ax; o.y = ay; o.z = az; o.w = aw;
  enc[(size_t)b * 128 + tid] = o;
}

}  // namespace

extern "C" void kernel_launch(void* const* d_in, const int* in_sizes, int n_in,
                              void* d_out, int out_size, void* d_ws, size_t ws_size,
                              hipStream_t stream) {
  const float* emb = (const float*)d_in[0];
  const float* Ws = (const float*)d_in[1];
  const float* Wn = (const float*)d_in[2];
  const float* Wr = (const float*)d_in[3];
  const float* Wt = (const float*)d_in[4];
  const int* cid = (const int*)d_in[5];
  const int* relid = (const int*)d_in[6];
  const int* headp = (const int*)d_in[7];
  const int* tailp = (const int*)d_in[8];
  const int* lblp = (const int*)d_in[9];
  float* out = (float*)d_out;

  // ---- workspace layout (bytes), <= 88 MB ----
  char* wsp = (char*)d_ws;
  ushort* Xa  = (ushort*)(wsp);                         // 16 MB (X ping: hop-0 in, hop-1 out)
  ushort* R1  = (ushort*)(wsp + (16ull << 20));         // 64 MB (rel after hop 1)
  ushort* Wsb = (ushort*)(wsp + (80ull << 20));         // 1 MB (2 hops)
  ushort* Wnb = (ushort*)(wsp + (81ull << 20));         // 1 MB
  ushort* Wrb = (ushort*)(wsp + (82ull << 20));         // 0.5 MB (hop 1 only)
  ushort* Wcb = (ushort*)(wsp + (82ull << 20) + (512ull << 10));  // 0.5 MB Wcomb
  ushort* Wtb = (ushort*)(wsp + (83ull << 20));         // 1.5 MB
  int* deg      = (int*)(wsp + (85ull << 20));          // 64 KB
  int* rowstart = deg + kB * kM;                        // 64 KB
  int* fillptr  = rowstart + kB * kM;                   // 64 KB
  int* epack    = fillptr + kB * kM;                    // 512 KB
  float* part   = (float*)(wsp + (87ull << 20));        // 0.5 MB

  // ---- d_out region doubles as hop-intermediate scratch (dead before MODE2) ----
  char* outc = (char*)d_out;
  ushort* R0 = (ushort*)(outc);                  // 64 MB (gathered rel)
  ushort* Xb = (ushort*)(outc + (64ull << 20));  // 16 MB (X pong: hop-0 out)
  ushort* Ub = (ushort*)(outc + (80ull << 20));  // 16 MB (ends at 96 MB < 128 MB)
  float* ENC = out + (size_t)kB * kT * kD;

  // weights -> bf16 (+ Wcomb fold of hop-2 Wr into Wt middle segment)
  cvt_bf16_k<<<512, 256, 0, stream>>>((const float4*)Ws, (ushort4*)Wsb, 2 * kD * kD / 4);
  cvt_bf16_k<<<512, 256, 0, stream>>>((const float4*)Wn, (ushort4*)Wnb, 2 * kD * kD / 4);
  cvt_bf16_k<<<256, 256, 0, stream>>>((const float4*)Wr, (ushort4*)Wrb, kD * kD / 4);
  cvt_bf16_k<<<768, 256, 0, stream>>>((const float4*)Wt, (ushort4*)Wtb, kD * 1536 / 4);
  wcomb_k<<<128, 512, 0, stream>>>(Wr + (size_t)kD * kD, Wt, Wcb);

  // gather embeddings -> bf16
  gather_bf16_k<<<(kB * kM * 128) / 256, 256, 0, stream>>>(
      (const float4*)emb, cid, (ushort4*)Xa, kB * kM);
  gather_bf16_k<<<(kB * kT * 128) / 256, 256, 0, stream>>>(
      (const float4*)emb, relid, (ushort4*)R0, kB * kT);

  // CSR build: zero -> count -> scan -> fill -> per-node sort (deterministic)
  zero_k<<<(kB * kM + 255) / 256, 256, 0, stream>>>(deg, kB * kM);
  deg_count_k<<<(kB * kT + 255) / 256, 256, 0, stream>>>(headp, tailp, lblp, deg);
  scan_k<<<kB, 1024, 0, stream>>>(deg, rowstart, fillptr);
  fill_k<<<(kB * kT + 255) / 256, 256, 0, stream>>>(headp, tailp, lblp, fillptr, epack);
  sort_k<<<(kB * kM + 255) / 256, 256, 0, stream>>>(rowstart, deg, epack);

  // ---- hop 1: X0(Xa) -> X1(Xb), rel0(R0) -> rel1(R1) ----
  compute_upd_k<<<kB * kM, 128, 0, stream>>>(
      (const ushort4*)Xa, (const ushort4*)R0, deg, rowstart, epack, (ushort4*)Ub);
  mfma_gemm_k<0><<<(kB * kM / 128) * 4, 256, 0, stream>>>(
      Xa, Ub, nullptr, Wsb, Wnb, nullptr, nullptr, nullptr, Xb);
  mfma_gemm_k<1><<<(kB * kT / 128) * 4, 256, 0, stream>>>(
      nullptr, nullptr, R0, Wrb, nullptr, nullptr, nullptr, nullptr, R1);

  // ---- hop 2: X1(Xb) -> X2(Xa); rel2 GEMM folded into Wcomb ----
  compute_upd_k<<<kB * kM, 128, 0, stream>>>(
      (const ushort4*)Xb, (const ushort4*)R1, deg, rowstart, epack, (ushort4*)Ub);
  mfma_gemm_k<0><<<(kB * kM / 128) * 4, 256, 0, stream>>>(
      Xb, Ub, nullptr, Wsb + (size_t)kD * kD, Wnb + (size_t)kD * kD,
      nullptr, nullptr, nullptr, Xa);

  // ---- final triple GEMM: out = X2[head]@Wt1^T + rel1@Wcomb^T + X2[tail]@Wt3^T ----
  mfma_gemm_k<2><<<(kB * kT / 128) * 4, 256, 0, stream>>>(
      Xa, nullptr, R1, Wtb, Wcb, headp, tailp, out, nullptr);

  // encoded_cause = sum over T
  reduce1_k<<<kB * 16, 128, 0, stream>>>((const float4*)out, (float4*)part);
  reduce2_k<<<kB, 128, 0, stream>>>((const float4*)part, (float4*)ENC);
}